// Round 2
// baseline (153.859 us; speedup 1.0000x reference)
//
#include <hip/hip_runtime.h>

#define B_SZ   1024
#define OUT_SZ 512
#define IN_SZ  1024
#define KK     2048            // merged K: [x^2 | x] · [u^2 | -2u^2w]

#define MB 64                  // b rows per block
#define NB 64                  // o rows per block
#define KSPLIT 4
#define KSL (KK / KSPLIT)      // 512 k per block
#define CH  64                 // k per chunk
#define NCH (KSL / CH)         // 8 chunks per block
#define NKC (KK / CH)          // 32 chunks total
#define CHUNK_ENT 512          // 16B entries per chunk image: 2(s)*4(frag)*64(slot)
#define DEPTH 4                // LDS ring depth (3 stages in flight)

typedef __bf16 bf16x8 __attribute__((ext_vector_type(8)));
typedef float  f32x4  __attribute__((ext_vector_type(4)));

// workspace layout (bytes)
#define PART_BYTES ((size_t)KSPLIT * B_SZ * OUT_SZ * 4)               // 8 MB
#define AIMG_OFF   PART_BYTES
#define AIMG_BYTES ((size_t)(B_SZ / MB) * NKC * CHUNK_ENT * 16)       // 4 MB
#define BIMG_OFF   (AIMG_OFF + AIMG_BYTES)
#define BIMG_BYTES ((size_t)(OUT_SZ / NB) * NKC * CHUNK_ENT * 16)     // 2 MB
#define RB_OFF     (BIMG_OFF + BIMG_BYTES)
#define CNT_OFF    (RB_OFF + OUT_SZ * 4)

// ---------------------------------------------------------------------------
// Prep: build bf16 fragment images in the exact LDS layout rbf_gemm stages.
// Entry e: slot=e&63, frag=(e>>6)&3, s=(e>>8)&1, kc=(e>>9)&31, tile=e>>14
//   row = tile*64 + frag*16 + (slot&15);  k0 = kc*64 + s*32 + (slot>>4)*8
// A' rows are b: k<1024 -> x^2, else x.   B' rows are o: k<1024 -> u^2, else -2u^2w.
// rbias[o] = sum_i (u*w)^2 (fp32). Also zeroes the split-k tile counters.
// ---------------------------------------------------------------------------
__global__ __launch_bounds__(256) void rbf_prep(
    const float* __restrict__ x, const float* __restrict__ w,
    const float* __restrict__ u, __bf16* __restrict__ Aimg,
    __bf16* __restrict__ Bimg, float* __restrict__ rbias,
    int* __restrict__ cnt)
{
    const int bid = blockIdx.x, t = threadIdx.x;
    if (bid < 1024) {                               // A image: 262144 entries
        const int e    = (bid << 8) + t;
        const int slot = e & 63;
        const int frag = (e >> 6) & 3;
        const int s    = (e >> 8) & 1;
        const int kc   = (e >> 9) & 31;
        const int mT   = e >> 14;
        const int row  = mT * 64 + frag * 16 + (slot & 15);
        const int k0   = kc * 64 + s * 32 + (slot >> 4) * 8;
        const float* src = &x[(size_t)row * IN_SZ + (k0 & (IN_SZ - 1))];
        float4 v0 = *(const float4*)src;
        float4 v1 = *(const float4*)(src + 4);
        float vv[8] = {v0.x, v0.y, v0.z, v0.w, v1.x, v1.y, v1.z, v1.w};
        bf16x8 o8;
        if (k0 < IN_SZ) {                           // wave-uniform (kc uniform per block)
            #pragma unroll
            for (int j = 0; j < 8; ++j) o8[j] = (__bf16)(vv[j] * vv[j]);
        } else {
            #pragma unroll
            for (int j = 0; j < 8; ++j) o8[j] = (__bf16)vv[j];
        }
        *(bf16x8*)&Aimg[(size_t)e * 8] = o8;
    } else if (bid < 1536) {                        // B image: 131072 entries
        const int e    = ((bid - 1024) << 8) + t;
        const int slot = e & 63;
        const int frag = (e >> 6) & 3;
        const int s    = (e >> 8) & 1;
        const int kc   = (e >> 9) & 31;
        const int nT   = e >> 14;
        const int row  = nT * 64 + frag * 16 + (slot & 15);
        const int k0   = kc * 64 + s * 32 + (slot >> 4) * 8;
        const size_t off = (size_t)row * IN_SZ + (k0 & (IN_SZ - 1));
        float4 u0 = *(const float4*)&u[off];
        float4 u1 = *(const float4*)&u[off + 4];
        float uu[8] = {u0.x, u0.y, u0.z, u0.w, u1.x, u1.y, u1.z, u1.w};
        bf16x8 o8;
        if (k0 < IN_SZ) {
            #pragma unroll
            for (int j = 0; j < 8; ++j) o8[j] = (__bf16)(uu[j] * uu[j]);
        } else {
            float4 w0 = *(const float4*)&w[off];
            float4 w1 = *(const float4*)&w[off + 4];
            float ww[8] = {w0.x, w0.y, w0.z, w0.w, w1.x, w1.y, w1.z, w1.w};
            #pragma unroll
            for (int j = 0; j < 8; ++j) o8[j] = (__bf16)(-2.f * uu[j] * uu[j] * ww[j]);
        }
        *(bf16x8*)&Bimg[(size_t)e * 8] = o8;
    } else if (bid < 1552) {                        // rbias: 16 blocks x 32 rows
        const int o = ((bid - 1536) << 5) + (t >> 3);
        const size_t base = (size_t)o * IN_SZ + (size_t)(t & 7) * 128;
        float s = 0.f;
        for (int k2 = 0; k2 < 128; k2 += 4) {
            float4 uu = *(const float4*)&u[base + k2];
            float4 ww = *(const float4*)&w[base + k2];
            float p0 = uu.x * ww.x, p1 = uu.y * ww.y;
            float p2 = uu.z * ww.z, p3 = uu.w * ww.w;
            s = fmaf(p0, p0, s); s = fmaf(p1, p1, s);
            s = fmaf(p2, p2, s); s = fmaf(p3, p3, s);
        }
        s += __shfl_xor(s, 1);
        s += __shfl_xor(s, 2);
        s += __shfl_xor(s, 4);
        if ((t & 7) == 0) rbias[o] = s;
    } else {                                        // zero split-k counters
        if (t < (B_SZ / MB) * (OUT_SZ / NB)) cnt[t] = 0;
    }
}

// direct global->LDS DMA, 16B per lane (dest = wave-uniform base + lane*16)
__device__ __forceinline__ void gld_lds16(const __bf16* g, __bf16* l) {
    __builtin_amdgcn_global_load_lds(
        (const __attribute__((address_space(1))) void*)g,
        (__attribute__((address_space(3))) void*)l, 16, 0, 0);
}

// ---------------------------------------------------------------------------
// GEMM + split-k finish. Depth-4 ring buffer, counted vmcnt (never 0 in the
// main loop) so 3 chunk-stages stay in flight across barriers; the barrier
// only orders LDS visibility, it no longer drains the load queue.
// Last-arriving kz block per tile sums the other slices, applies rbias +
// exp + andor mix, writes out.
// ---------------------------------------------------------------------------
__global__ __launch_bounds__(256) void rbf_gemm(
    const __bf16* __restrict__ Aimg, const __bf16* __restrict__ Bimg,
    float* __restrict__ part, const float* __restrict__ rbias,
    const float* __restrict__ andor, int* __restrict__ cnt,
    float* __restrict__ out)
{
    __shared__ __bf16 Asm[DEPTH][CHUNK_ENT * 8];    // 4 x 8 KB
    __shared__ __bf16 Bsm[DEPTH][CHUNK_ENT * 8];    // 4 x 8 KB
    __shared__ int lastFlag;

    const int t = threadIdx.x, lane = t & 63;
    const int wv = t >> 6, wm = wv >> 1, wn = wv & 1;
    const int mT = blockIdx.x, nT = blockIdx.y, kz = blockIdx.z;

    f32x4 acc[2][2] = {};

    const __bf16* gA = &Aimg[(size_t)(mT * NKC + kz * NCH) * CHUNK_ENT * 8];
    const __bf16* gB = &Bimg[(size_t)(nT * NKC + kz * NCH) * CHUNK_ENT * 8];

    auto stage = [&](int buf, int c) {
        const __bf16* ga = gA + (size_t)c * CHUNK_ENT * 8;
        const __bf16* gb = gB + (size_t)c * CHUNK_ENT * 8;
        gld_lds16(ga + (size_t)t * 8,         &Asm[buf][t * 8]);
        gld_lds16(ga + (size_t)(t + 256) * 8, &Asm[buf][(t + 256) * 8]);
        gld_lds16(gb + (size_t)t * 8,         &Bsm[buf][t * 8]);
        gld_lds16(gb + (size_t)(t + 256) * 8, &Bsm[buf][(t + 256) * 8]);
    };

    auto compute = [&](int buf) {
        const __bf16* Ab = Asm[buf];
        const __bf16* Bb = Bsm[buf];
        #pragma unroll
        for (int s = 0; s < 2; ++s) {
            bf16x8 a0 = *(const bf16x8*)&Ab[((s * 4 + wm * 2    ) * 64 + lane) * 8];
            bf16x8 a1 = *(const bf16x8*)&Ab[((s * 4 + wm * 2 + 1) * 64 + lane) * 8];
            bf16x8 b0 = *(const bf16x8*)&Bb[((s * 4 + wn * 2    ) * 64 + lane) * 8];
            bf16x8 b1 = *(const bf16x8*)&Bb[((s * 4 + wn * 2 + 1) * 64 + lane) * 8];
            acc[0][0] = __builtin_amdgcn_mfma_f32_16x16x32_bf16(a0, b0, acc[0][0], 0, 0, 0);
            acc[0][1] = __builtin_amdgcn_mfma_f32_16x16x32_bf16(a0, b1, acc[0][1], 0, 0, 0);
            acc[1][0] = __builtin_amdgcn_mfma_f32_16x16x32_bf16(a1, b0, acc[1][0], 0, 0, 0);
            acc[1][1] = __builtin_amdgcn_mfma_f32_16x16x32_bf16(a1, b1, acc[1][1], 0, 0, 0);
        }
    };

    stage(0, 0);
    stage(1, 1);
    stage(2, 2);

#define WAITV(N) asm volatile("s_waitcnt vmcnt(" #N ")" ::: "memory")
#define STEP(c, N) do {                                                   \
        WAITV(N);                         /* own stage-c loads done   */  \
        __builtin_amdgcn_s_barrier();     /* everyone's stage-c done  */  \
        __builtin_amdgcn_sched_barrier(0);                                \
        if ((c) + DEPTH - 1 < NCH)                                        \
            stage(((c) + DEPTH - 1) & (DEPTH - 1), (c) + DEPTH - 1);      \
        compute((c) & (DEPTH - 1));                                       \
    } while (0)

    STEP(0, 8); STEP(1, 8); STEP(2, 8); STEP(3, 8);
    STEP(4, 8); STEP(5, 8); STEP(6, 4); STEP(7, 0);
#undef STEP
#undef WAITV

    // ---- publish partial tile: C/D col = lane&15 (o), row = quad*4+reg (b)
    const int col = lane & 15, rq = lane >> 4;
    #pragma unroll
    for (int mi = 0; mi < 2; ++mi) {
        const int b = mT * MB + (wm * 2 + mi) * 16 + rq * 4;
        #pragma unroll
        for (int ni = 0; ni < 2; ++ni) {
            const int o = nT * NB + (wn * 2 + ni) * 16 + col;
            #pragma unroll
            for (int r = 0; r < 4; ++r)
                part[((size_t)kz * B_SZ + (b + r)) * OUT_SZ + o] = acc[mi][ni][r];
        }
    }
    __threadfence();                      // make stores agent-visible
    __syncthreads();                      // all threads' fenced stores ordered
    if (t == 0)
        lastFlag = (atomicAdd(&cnt[mT * (OUT_SZ / NB) + nT], 1) == KSPLIT - 1);
    __syncthreads();

    if (lastFlag) {                       // we are the 4th arriver for this tile
        __threadfence();                  // acquire: see other slices' stores
        #pragma unroll
        for (int mi = 0; mi < 2; ++mi) {
            const int b = mT * MB + (wm * 2 + mi) * 16 + rq * 4;
            #pragma unroll
            for (int ni = 0; ni < 2; ++ni) {
                const int o = nT * NB + (wn * 2 + ni) * 16 + col;
                const float rb = rbias[o];
                const float a  = andor[o];
                const float cf = 1.f - 2.f * a;
                #pragma unroll
                for (int r = 0; r < 4; ++r) {
                    float z = acc[mi][ni][r] + rb;
                    #pragma unroll
                    for (int k2 = 0; k2 < KSPLIT; ++k2)
                        if (k2 != kz)
                            z += *(const volatile float*)
                                 &part[((size_t)k2 * B_SZ + (b + r)) * OUT_SZ + o];
                    float y = __expf(-z);
                    out[(size_t)(b + r) * OUT_SZ + o] = fmaf(y, cf, a);
                }
            }
        }
    }
}

extern "C" void kernel_launch(void* const* d_in, const int* in_sizes, int n_in,
                              void* d_out, int out_size, void* d_ws, size_t ws_size,
                              hipStream_t stream) {
    const float* x = (const float*)d_in[0];   // [B, IN]
    const float* w = (const float*)d_in[1];   // [OUT, IN]
    const float* u = (const float*)d_in[2];   // [OUT, IN]
    const float* a = (const float*)d_in[3];   // [1, OUT]
    float* out = (float*)d_out;               // [B, OUT]

    float*  part  = (float*)d_ws;
    __bf16* Aimg  = (__bf16*)((char*)d_ws + AIMG_OFF);
    __bf16* Bimg  = (__bf16*)((char*)d_ws + BIMG_OFF);
    float*  rbias = (float*)((char*)d_ws + RB_OFF);
    int*    cnt   = (int*)((char*)d_ws + CNT_OFF);

    rbf_prep<<<dim3(1553), dim3(256), 0, stream>>>(x, w, u, Aimg, Bimg, rbias, cnt);
    rbf_gemm<<<dim3(B_SZ / MB, OUT_SZ / NB, KSPLIT), dim3(256), 0, stream>>>(
        Aimg, Bimg, part, rbias, a, cnt, out);
}

// Round 3
// 86.563 us; speedup vs baseline: 1.7774x; 1.7774x over previous
//
#include <hip/hip_runtime.h>

#define B_SZ   1024
#define OUT_SZ 512
#define IN_SZ  1024

#define NKC 32                 // 64-wide k-chunks over merged K=2048
#define CHUNK_ENT 512          // 16B entries per (64-row tile x 64-k chunk)

#define MBT 32                 // m rows per gemm block
#define NBT 32                 // o cols per gemm block

typedef __bf16 bf16x8 __attribute__((ext_vector_type(8)));
typedef float  f32x4  __attribute__((ext_vector_type(4)));

// workspace layout (bytes)
#define AIMG_BYTES ((size_t)16 * NKC * CHUNK_ENT * 16)   // 4 MB: [tile16][kc32][512]x16B
#define BIMG_OFF   AIMG_BYTES
#define BIMG_BYTES ((size_t)8  * NKC * CHUNK_ENT * 16)   // 2 MB: [tile8][kc32][512]x16B
#define RB_OFF     (BIMG_OFF + BIMG_BYTES)

// ---------------------------------------------------------------------------
// Prep: build bf16 fragment images, fully coalesced reads.
// Image entry e within a (tile,kc) chunk: e = (s*4+frag)*64 + quad*16 + row16
//   row = tile*64 + frag*16 + row16 ; k = kc*64 + s*32 + quad*8 + j
// A' (rows=b): k<1024 -> x^2, else x.   B' (rows=o): k<1024 -> u^2, else -2u^2w.
// rbias[o] = sum_i (u*w)^2 in fp32 (rank-1 term, kept out of the MFMA).
// Thread map: r = t>>2 (64 rows/block), c4 = t&3 (4 lanes sweep 64 floats/row):
// reads are 256B-contiguous per 4-lane group; writes are 256B-contiguous per
// 16-lane group.
// ---------------------------------------------------------------------------
__global__ __launch_bounds__(256) void rbf_prep(
    const float* __restrict__ x, const float* __restrict__ w,
    const float* __restrict__ u, __bf16* __restrict__ Aimg,
    __bf16* __restrict__ Bimg, float* __restrict__ rbias)
{
    const int bid = blockIdx.x, t = threadIdx.x;
    if (bid < 768) {                                 // image builders
        const bool isA = bid < 512;
        const int  rel = isA ? bid : bid - 512;      // tile*32 + kc
        const int  tile = rel >> 5, kc = rel & 31;
        const int  r = t >> 2, c4 = t & 3;
        const int  row = tile * 64 + r;
        const int  kb  = (kc & 15) * 64 + c4 * 16;   // source col in [0,1024)
        const bool firstHalf = (kc < 16);            // block-uniform

        float f[16];
        __bf16 g[16];
        if (isA) {
            const float4* src = (const float4*)&x[(size_t)row * IN_SZ + kb];
            #pragma unroll
            for (int q = 0; q < 4; ++q) *(float4*)&f[q * 4] = src[q];
            if (firstHalf) {
                #pragma unroll
                for (int j = 0; j < 16; ++j) g[j] = (__bf16)(f[j] * f[j]);
            } else {
                #pragma unroll
                for (int j = 0; j < 16; ++j) g[j] = (__bf16)f[j];
            }
        } else {
            const float4* su = (const float4*)&u[(size_t)row * IN_SZ + kb];
            #pragma unroll
            for (int q = 0; q < 4; ++q) *(float4*)&f[q * 4] = su[q];
            if (firstHalf) {
                #pragma unroll
                for (int j = 0; j < 16; ++j) g[j] = (__bf16)(f[j] * f[j]);
            } else {
                float fw[16];
                const float4* sw = (const float4*)&w[(size_t)row * IN_SZ + kb];
                #pragma unroll
                for (int q = 0; q < 4; ++q) *(float4*)&fw[q * 4] = sw[q];
                #pragma unroll
                for (int j = 0; j < 16; ++j)
                    g[j] = (__bf16)(-2.f * f[j] * f[j] * fw[j]);
            }
        }
        __bf16* dst = (isA ? Aimg : Bimg) + (size_t)rel * CHUNK_ENT * 8;
        #pragma unroll
        for (int h = 0; h < 2; ++h) {                // two 8-k segments
            const int idx2 = c4 * 2 + h;             // k-local / 8
            const int s = idx2 >> 2, quad = idx2 & 3;
            const int e = (s * 4 + (r >> 4)) * 64 + quad * 16 + (r & 15);
            bf16x8 o8;
            #pragma unroll
            for (int j = 0; j < 8; ++j) o8[j] = g[h * 8 + j];
            *(bf16x8*)&dst[(size_t)e * 8] = o8;
        }
    } else {                                         // rbias: 16 blocks x 32 rows
        const int o = ((bid - 768) << 5) + (t >> 3);
        const size_t base = (size_t)o * IN_SZ + (size_t)(t & 7) * 128;
        float s = 0.f;
        for (int k2 = 0; k2 < 128; k2 += 4) {
            float4 uu = *(const float4*)&u[base + k2];
            float4 ww = *(const float4*)&w[base + k2];
            float p0 = uu.x * ww.x, p1 = uu.y * ww.y;
            float p2 = uu.z * ww.z, p3 = uu.w * ww.w;
            s = fmaf(p0, p0, s); s = fmaf(p1, p1, s);
            s = fmaf(p2, p2, s); s = fmaf(p3, p3, s);
        }
        s += __shfl_xor(s, 1);
        s += __shfl_xor(s, 2);
        s += __shfl_xor(s, 4);
        if ((t & 7) == 0) rbias[o] = s;
    }
}

// ---------------------------------------------------------------------------
// GEMM + fused epilogue. Full K per block (no split-k, no part buffer).
// Reg-staged: bf16x8 global load -> ds_write_b128, single LDS buffer,
// 2 barriers/chunk, next-chunk loads issued a full compute-phase early
// (round-0's proven schedule). Lane-linear LDS: zero bank conflicts.
// ---------------------------------------------------------------------------
__global__ __launch_bounds__(256) void rbf_gemm(
    const __bf16* __restrict__ Aimg, const __bf16* __restrict__ Bimg,
    const float* __restrict__ rbias, const float* __restrict__ andor,
    float* __restrict__ out)
{
    __shared__ __bf16 Asm[256 * 8];                  // 4 KB: 256 entries
    __shared__ __bf16 Bsm[256 * 8];                  // 4 KB

    const int t = threadIdx.x, lane = t & 63;
    const int wv = t >> 6, wm = wv >> 1, wn = wv & 1;
    const int mT = blockIdx.x;                       // 0..31 (32-row tiles)
    const int nT = blockIdx.y;                       // 0..15 (32-col tiles)
    const int fbA = (mT & 1) * 2;                    // which half of the 64-row image tile
    const int fbB = (nT & 1) * 2;

    const __bf16* gA = Aimg + (size_t)(mT >> 1) * NKC * CHUNK_ENT * 8;
    const __bf16* gB = Bimg + (size_t)(nT >> 1) * NKC * CHUNK_ENT * 8;

    // per-thread chunk-local entry: t = (sE*2 + fiE)*64 + slE  (256 entries)
    const int sE = t >> 7, fiE = (t >> 6) & 1, slE = t & 63;
    const int eA = (((sE * 4 + fbA + fiE) * 64 + slE)) * 8;   // elem offset in chunk
    const int eB = (((sE * 4 + fbB + fiE) * 64 + slE)) * 8;

    f32x4 acc = {};
    bf16x8 ra, rb;
    auto load = [&](int c) {
        ra = *(const bf16x8*)&gA[(size_t)c * CHUNK_ENT * 8 + eA];
        rb = *(const bf16x8*)&gB[(size_t)c * CHUNK_ENT * 8 + eB];
    };

    load(0);
    for (int c = 0; c < NKC; ++c) {
        if (c) __syncthreads();                      // prior compute done with LDS
        *(bf16x8*)&Asm[t * 8] = ra;
        *(bf16x8*)&Bsm[t * 8] = rb;
        __syncthreads();                             // buffer ready
        if (c + 1 < NKC) load(c + 1);                // prefetch: hidden by compute
        #pragma unroll
        for (int s = 0; s < 2; ++s) {
            bf16x8 av = *(const bf16x8*)&Asm[((s * 2 + wm) * 64 + lane) * 8];
            bf16x8 bv = *(const bf16x8*)&Bsm[((s * 2 + wn) * 64 + lane) * 8];
            acc = __builtin_amdgcn_mfma_f32_16x16x32_bf16(av, bv, acc, 0, 0, 0);
        }
    }

    // C/D: col = lane&15 (o), row = quad*4 + reg (b) — verified mapping.
    const int col = lane & 15, rq = lane >> 4;
    const int b = mT * MBT + wm * 16 + rq * 4;
    const int o = nT * NBT + wn * 16 + col;
    const float rbv = rbias[o];
    const float a   = andor[o];
    const float cf  = 1.f - 2.f * a;
    #pragma unroll
    for (int r = 0; r < 4; ++r) {
        float y = __expf(-(acc[r] + rbv));
        out[(size_t)(b + r) * OUT_SZ + o] = fmaf(y, cf, a);
    }
}

extern "C" void kernel_launch(void* const* d_in, const int* in_sizes, int n_in,
                              void* d_out, int out_size, void* d_ws, size_t ws_size,
                              hipStream_t stream) {
    const float* x = (const float*)d_in[0];   // [B, IN]
    const float* w = (const float*)d_in[1];   // [OUT, IN]
    const float* u = (const float*)d_in[2];   // [OUT, IN]
    const float* a = (const float*)d_in[3];   // [1, OUT]
    float* out = (float*)d_out;               // [B, OUT]

    __bf16* Aimg  = (__bf16*)d_ws;
    __bf16* Bimg  = (__bf16*)((char*)d_ws + BIMG_OFF);
    float*  rbias = (float*)((char*)d_ws + RB_OFF);

    rbf_prep<<<dim3(784), dim3(256), 0, stream>>>(x, w, u, Aimg, Bimg, rbias);
    rbf_gemm<<<dim3(B_SZ / MBT, OUT_SZ / NBT), dim3(256), 0, stream>>>(
        Aimg, Bimg, rbias, a, out);
}

// Round 4
// 75.868 us; speedup vs baseline: 2.0280x; 1.1410x over previous
//
#include <hip/hip_runtime.h>

#define B_SZ   1024
#define OUT_SZ 512
#define IN_SZ  1024

#define MB 64                  // b-rows per block
#define NB 32                  // o-rows per block
#define NKC 16                 // 64-wide k chunks, full K per block

typedef __bf16 bf16x8 __attribute__((ext_vector_type(8)));
typedef __bf16 bf16x4 __attribute__((ext_vector_type(4)));
typedef float  f32x4  __attribute__((ext_vector_type(4)));

// R0's proven fragment-native LDS layout (measured 0 bank conflicts):
//   slot = quad*16 + ((row16 ^ quad) & 15)
// A segs: 0 = x^2, 1 = x    (4 m-frags)
// B segs: 0 = u^2, 1 = -2u^2w  (2 n-frags); the (uw)^2 rank-1 term is
// accumulated in fp32 VALU instead of MFMA (exact, cheaper).
#define A_IDX(seg, s, mf, slot) (((((seg)*2 + (s))*4 + (mf))*64 + (slot))*8)
#define B_IDX(seg, s, nf, slot) (((((seg)*2 + (s))*2 + (nf))*64 + (slot))*8)

// Single fused kernel: raw x,u,w -> bf16 frags in LDS -> MFMA over full K
// -> fused exp/andor epilogue. No workspace, no second kernel.
__global__ __launch_bounds__(512) void rbf_one(
    const float* __restrict__ x, const float* __restrict__ w,
    const float* __restrict__ u, const float* __restrict__ andor,
    float* __restrict__ out)
{
    __shared__ __bf16 Asm[2 * 2 * 4 * 64 * 8];   // 16 KB
    __shared__ __bf16 Bsm[2 * 2 * 2 * 64 * 8];   // 8 KB
    __shared__ float  r_lds[NB];

    const int t    = threadIdx.x;
    const int lane = t & 63;
    const int wv   = t >> 6;                     // 0..7
    const int wm   = wv >> 1;                    // m-frag 0..3
    const int wn   = wv & 1;                     // n-frag 0..1

    // XCD-bijective swizzle: 256 blocks, 8 XCDs -> each XCD owns 2 nT strips
    // (u,w strip = 256 KB, resident in that XCD's 4 MB L2).
    const int bid = blockIdx.x;
    const int swz = (bid & 7) * 32 + (bid >> 3);
    const int mT = swz & 15, nT = swz >> 4;
    const int mBase = mT * MB, nBase = nT * NB;

    f32x4 acc = {};
    float rp = 0.f;                              // per-thread (uw)^2 partial

    // thread map: 16 lanes sweep 64 floats (256B contiguous) per row.
    const int arow = t >> 4;                     // 0..31 (i=1 adds 32)
    const int akl  = (t & 15) * 4;               // k-local 0..60
    const int brow = t >> 4;                     // 0..31 (fixed u/w row)

    float4 xr[2], ur, wr;
    auto load_regs = [&](int c) {
        const int gk = c * 64 + akl;
        xr[0] = *(const float4*)&x[(size_t)(mBase + arow)      * IN_SZ + gk];
        xr[1] = *(const float4*)&x[(size_t)(mBase + 32 + arow) * IN_SZ + gk];
        ur    = *(const float4*)&u[(size_t)(nBase + brow)      * IN_SZ + gk];
        wr    = *(const float4*)&w[(size_t)(nBase + brow)      * IN_SZ + gk];
    };

    const int sW   = akl >> 5;                   // which 32-k MFMA step
    const int quad = (akl >> 3) & 3;
    const int j0   = akl & 7;                    // 0 or 4

    auto write_lds = [&]() {
        #pragma unroll
        for (int i = 0; i < 2; ++i) {            // A: rows arow, arow+32
            const int row   = i * 32 + arow;
            const int frag  = row >> 4;
            const int slot  = quad * 16 + (((row & 15) ^ quad) & 15);
            float v[4] = {xr[i].x, xr[i].y, xr[i].z, xr[i].w};
            bf16x4 a0, a1;
            #pragma unroll
            for (int e = 0; e < 4; ++e) {
                a0[e] = (__bf16)(v[e] * v[e]);
                a1[e] = (__bf16)v[e];
            }
            *(bf16x4*)&Asm[A_IDX(0, sW, frag, slot) + j0] = a0;
            *(bf16x4*)&Asm[A_IDX(1, sW, frag, slot) + j0] = a1;
        }
        {                                        // B: row brow
            const int frag = brow >> 4;
            const int slot = quad * 16 + (((brow & 15) ^ quad) & 15);
            float uv[4] = {ur.x, ur.y, ur.z, ur.w};
            float wv4[4] = {wr.x, wr.y, wr.z, wr.w};
            bf16x4 b0, b1;
            #pragma unroll
            for (int e = 0; e < 4; ++e) {
                float u2 = uv[e] * uv[e];
                float p  = uv[e] * wv4[e];
                b0[e] = (__bf16)u2;
                b1[e] = (__bf16)(-2.f * u2 * wv4[e]);
                rp = fmaf(p, p, rp);             // exact rank-1 term
            }
            *(bf16x4*)&Bsm[B_IDX(0, sW, frag, slot) + j0] = b0;
            *(bf16x4*)&Bsm[B_IDX(1, sW, frag, slot) + j0] = b1;
        }
    };

    // read slot (same swizzle) -> conflict-free b128 reads (R0-proven)
    const int r_quad = lane >> 4;
    const int r_slot = r_quad * 16 + (((lane & 15) ^ r_quad) & 15);

    load_regs(0);
    for (int c = 0; c < NKC; ++c) {
        __syncthreads();                         // prev MFMAs done with LDS
        write_lds();
        __syncthreads();                         // buffer ready
        if (c + 1 < NKC) load_regs(c + 1);       // prefetch behind MFMAs
        #pragma unroll
        for (int seg = 0; seg < 2; ++seg)
            #pragma unroll
            for (int s2 = 0; s2 < 2; ++s2) {
                bf16x8 am = *(const bf16x8*)&Asm[A_IDX(seg, s2, wm, r_slot)];
                bf16x8 bn = *(const bf16x8*)&Bsm[B_IDX(seg, s2, wn, r_slot)];
                acc = __builtin_amdgcn_mfma_f32_16x16x32_bf16(am, bn, acc, 0, 0, 0);
            }
    }

    // reduce (uw)^2 partials: 16 lanes per o-row
    rp += __shfl_xor(rp, 1);
    rp += __shfl_xor(rp, 2);
    rp += __shfl_xor(rp, 4);
    rp += __shfl_xor(rp, 8);
    if ((lane & 15) == 0) r_lds[brow] = rp;
    __syncthreads();

    // C/D: col = lane&15 (o), row = quad*4 + reg (b) — R0-verified mapping
    const int col = lane & 15, rq = lane >> 4;
    const int b = mBase + wm * 16 + rq * 4;
    const int o = nBase + wn * 16 + col;
    const float rv = r_lds[wn * 16 + col];
    const float a  = andor[o];
    const float cf = 1.f - 2.f * a;
    #pragma unroll
    for (int r = 0; r < 4; ++r) {
        float y = __expf(-(acc[r] + rv));
        out[(size_t)(b + r) * OUT_SZ + o] = fmaf(y, cf, a);
    }
}

extern "C" void kernel_launch(void* const* d_in, const int* in_sizes, int n_in,
                              void* d_out, int out_size, void* d_ws, size_t ws_size,
                              hipStream_t stream) {
    const float* x = (const float*)d_in[0];   // [B, IN]
    const float* w = (const float*)d_in[1];   // [OUT, IN]
    const float* u = (const float*)d_in[2];   // [OUT, IN]
    const float* a = (const float*)d_in[3];   // [1, OUT]
    float* out = (float*)d_out;               // [B, OUT]

    rbf_one<<<dim3((B_SZ / MB) * (OUT_SZ / NB)), dim3(512), 0, stream>>>(
        x, w, u, a, out);
}

// Round 5
// 73.404 us; speedup vs baseline: 2.0961x; 1.0336x over previous
//
#include <hip/hip_runtime.h>

#define B_SZ   1024
#define OUT_SZ 512
#define IN_SZ  1024

#define MB 32                  // b-rows per block
#define NB 32                  // o-rows per block
#define CH 128                 // raw k per chunk
#define NKC (IN_SZ / CH)       // 8 chunks, full K per block

typedef __bf16 bf16x8 __attribute__((ext_vector_type(8)));
typedef __bf16 bf16x4 __attribute__((ext_vector_type(4)));
typedef float  f32x4  __attribute__((ext_vector_type(4)));

// R0-proven fragment-native LDS layout (measured 0 bank conflicts):
//   slot = quad*16 + ((row16 ^ quad) & 15)
// dims: seg(2) x s(4) x frag(2) x slot(64) x j(8)
// A segs: 0 = x^2, 1 = x ;  B segs: 0 = u^2, 1 = -2u^2w
// (uw)^2 rank-1 term accumulated exactly in fp32 VALU (not MFMA).
#define A_IDX(seg, s, f, slot) (((((seg)*4 + (s))*2 + (f))*64 + (slot))*8)
#define B_IDX(seg, s, f, slot) (((((seg)*4 + (s))*2 + (f))*64 + (slot))*8)

// One fused kernel. 512 threads = 8 waves: wave -> (wm, wn, ks) where ks
// splits the 4 MFMA k-steps of each chunk in half; the two ks partials are
// merged through LDS at the end. Grid 512 -> 2 blocks/CU (stall overlap),
// 4 waves/SIMD.
__global__ __launch_bounds__(512, 4) void rbf_one(
    const float* __restrict__ x, const float* __restrict__ w,
    const float* __restrict__ u, const float* __restrict__ andor,
    float* __restrict__ out)
{
    __shared__ __bf16 Asm[2 * 4 * 2 * 64 * 8];   // 16 KB
    __shared__ __bf16 Bsm[2 * 4 * 2 * 64 * 8];   // 16 KB
    __shared__ float  accsm[4 * 64 * 4];         // 4 KB: ks=1 partials
    __shared__ float  r_lds[NB];

    const int t    = threadIdx.x;
    const int lane = t & 63;
    const int wv   = t >> 6;                     // 0..7
    const int ks   = wv & 1;                     // k-half
    const int wn   = (wv >> 1) & 1;              // n-frag
    const int wm   = (wv >> 2) & 1;              // m-frag

    // XCD-bijective swizzle: 512 blocks, 64/XCD -> each XCD owns 2 nT strips
    // (u,w slice = 512 KB, resident in that XCD's 4 MB L2).
    const int bid = blockIdx.x;
    const int swz = (bid & 7) * 64 + (bid >> 3);
    const int nT = swz >> 5, mT = swz & 31;
    const int mBase = mT * MB, nBase = nT * NB;

    f32x4 acc = {};
    float rp = 0.f;                              // per-thread (uw)^2 partial

    // staging map: row = t>>4 (one x row AND one u/w row per thread),
    // 16 lanes sweep 64 floats (256B contiguous) per row, h doubles to 128.
    const int row = t >> 4;                      // 0..31
    const int k4  = (t & 15) * 4;

    float4 xr[2], ur[2], wr[2];
    auto load_regs = [&](int c) {
        #pragma unroll
        for (int h = 0; h < 2; ++h) {
            const int gk = c * CH + h * 64 + k4;
            xr[h] = *(const float4*)&x[(size_t)(mBase + row) * IN_SZ + gk];
            ur[h] = *(const float4*)&u[(size_t)(nBase + row) * IN_SZ + gk];
            wr[h] = *(const float4*)&w[(size_t)(nBase + row) * IN_SZ + gk];
        }
    };

    auto write_lds = [&]() {
        #pragma unroll
        for (int h = 0; h < 2; ++h) {
            const int kl   = h * 64 + k4;
            const int sW   = kl >> 5;
            const int quad = (kl >> 3) & 3;
            const int j0   = kl & 7;
            const int frag = row >> 4;
            const int slot = quad * 16 + (((row & 15) ^ quad) & 15);
            float xv[4]  = {xr[h].x, xr[h].y, xr[h].z, xr[h].w};
            float uv[4]  = {ur[h].x, ur[h].y, ur[h].z, ur[h].w};
            float wv4[4] = {wr[h].x, wr[h].y, wr[h].z, wr[h].w};
            bf16x4 a0, a1, b0, b1;
            #pragma unroll
            for (int e = 0; e < 4; ++e) {
                float xe = xv[e], ue = uv[e], we = wv4[e];
                float u2 = ue * ue, p = ue * we;
                a0[e] = (__bf16)(xe * xe);
                a1[e] = (__bf16)xe;
                b0[e] = (__bf16)u2;
                b1[e] = (__bf16)(-2.f * u2 * we);
                rp = fmaf(p, p, rp);             // exact rank-1 term
            }
            *(bf16x4*)&Asm[A_IDX(0, sW, frag, slot) + j0] = a0;
            *(bf16x4*)&Asm[A_IDX(1, sW, frag, slot) + j0] = a1;
            *(bf16x4*)&Bsm[B_IDX(0, sW, frag, slot) + j0] = b0;
            *(bf16x4*)&Bsm[B_IDX(1, sW, frag, slot) + j0] = b1;
        }
    };

    // read slot (same swizzle) -> conflict-free b128 reads (R0-proven)
    const int r_quad = lane >> 4;
    const int r_slot = r_quad * 16 + (((lane & 15) ^ r_quad) & 15);

    load_regs(0);
    for (int c = 0; c < NKC; ++c) {
        if (c) __syncthreads();                  // prev MFMAs done with LDS
        write_lds();
        __syncthreads();                         // buffer ready
        if (c + 1 < NKC) load_regs(c + 1);       // prefetch behind MFMAs
        #pragma unroll
        for (int seg = 0; seg < 2; ++seg)
            #pragma unroll
            for (int sh = 0; sh < 2; ++sh) {
                bf16x8 am = *(const bf16x8*)&Asm[A_IDX(seg, ks * 2 + sh, wm, r_slot)];
                bf16x8 bn = *(const bf16x8*)&Bsm[B_IDX(seg, ks * 2 + sh, wn, r_slot)];
                acc = __builtin_amdgcn_mfma_f32_16x16x32_bf16(am, bn, acc, 0, 0, 0);
            }
    }

    // rank-1 reduce: 16 lanes per o-row
    rp += __shfl_xor(rp, 1);
    rp += __shfl_xor(rp, 2);
    rp += __shfl_xor(rp, 4);
    rp += __shfl_xor(rp, 8);
    if ((lane & 15) == 0) r_lds[row] = rp;

    __syncthreads();                             // LDS free for accsm reuse
    if (ks == 1)
        *(f32x4*)&accsm[((wm * 2 + wn) * 64 + lane) * 4] = acc;
    __syncthreads();

    if (ks == 0) {
        f32x4 o4 = *(const f32x4*)&accsm[((wm * 2 + wn) * 64 + lane) * 4];
        // C/D: col = lane&15 (o), row = quad*4 + reg (b) — verified mapping
        const int col = lane & 15, rq = lane >> 4;
        const int b = mBase + wm * 16 + rq * 4;
        const int o = nBase + wn * 16 + col;
        const float rv = r_lds[wn * 16 + col];
        const float a  = andor[o];
        const float cf = 1.f - 2.f * a;
        #pragma unroll
        for (int r = 0; r < 4; ++r) {
            float y = __expf(-(acc[r] + o4[r] + rv));
            out[(size_t)(b + r) * OUT_SZ + o] = fmaf(y, cf, a);
        }
    }
}

extern "C" void kernel_launch(void* const* d_in, const int* in_sizes, int n_in,
                              void* d_out, int out_size, void* d_ws, size_t ws_size,
                              hipStream_t stream) {
    const float* x = (const float*)d_in[0];   // [B, IN]
    const float* w = (const float*)d_in[1];   // [OUT, IN]
    const float* u = (const float*)d_in[2];   // [OUT, IN]
    const float* a = (const float*)d_in[3];   // [1, OUT]
    float* out = (float*)d_out;               // [B, OUT]

    rbf_one<<<dim3((B_SZ / MB) * (OUT_SZ / NB)), dim3(512), 0, stream>>>(
        x, w, u, a, out);
}

// Round 7
// 73.187 us; speedup vs baseline: 2.1023x; 1.0030x over previous
//
#include <hip/hip_runtime.h>

#define B_SZ   1024
#define OUT_SZ 512
#define IN_SZ  1024

#define MB 32                  // b-rows per block
#define NB 32                  // o-rows per block
#define CH 128                 // raw k per chunk
#define NKC (IN_SZ / CH)       // 8 chunks, full K per block

typedef __bf16 bf16x8 __attribute__((ext_vector_type(8)));
typedef __bf16 bf16x4 __attribute__((ext_vector_type(4)));
typedef float  f32x4  __attribute__((ext_vector_type(4)));

// R0-proven fragment-native LDS layout (measured 0 bank conflicts):
//   slot = quad*16 + ((row16 ^ quad) & 15)
// dims: seg(2) x s(4) x frag(2) x slot(64) x j(8)
// A segs: 0 = x^2, 1 = x ;  B segs: 0 = u^2, 1 = -2u^2w
// (uw)^2 rank-1 term accumulated exactly in fp32 VALU (not MFMA).
#define A_IDX(seg, s, f, slot) (((((seg)*4 + (s))*2 + (f))*64 + (slot))*8)
#define B_IDX(seg, s, f, slot) (((((seg)*4 + (s))*2 + (f))*64 + (slot))*8)

// One fused kernel. 512 threads = 8 waves: wave -> (wm, wn, ks); ks splits
// the 4 MFMA k-steps per chunk, partials merged via LDS at the end.
// Pipeline: double-buffered LDS (1 barrier/chunk) + 2-deep register
// prefetch (each load set gets a full iteration to land).
__global__ __launch_bounds__(512, 4) void rbf_one(
    const float* __restrict__ x, const float* __restrict__ w,
    const float* __restrict__ u, const float* __restrict__ andor,
    float* __restrict__ out)
{
    __shared__ __bf16 Asm[2][2 * 4 * 2 * 64 * 8];   // 2 x 16 KB
    __shared__ __bf16 Bsm[2][2 * 4 * 2 * 64 * 8];   // 2 x 16 KB
    __shared__ float  accsm[4 * 64 * 4];            // 4 KB: ks=1 partials
    __shared__ float  r_lds[NB];

    const int t    = threadIdx.x;
    const int lane = t & 63;
    const int wv   = t >> 6;                     // 0..7
    const int ks   = wv & 1;                     // k-half
    const int wn   = (wv >> 1) & 1;              // n-frag
    const int wm   = (wv >> 2) & 1;              // m-frag

    // XCD-bijective swizzle: 512 blocks, 64/XCD -> each XCD owns 2 nT strips
    // (u,w slice = 512 KB, resident in that XCD's 4 MB L2).
    const int bid = blockIdx.x;
    const int swz = (bid & 7) * 64 + (bid >> 3);
    const int nT = swz >> 5, mT = swz & 31;
    const int mBase = mT * MB, nBase = nT * NB;

    f32x4 acc = {};
    float rp = 0.f;                              // per-thread (uw)^2 partial

    // staging map: row = t>>4 (one x row AND one u/w row per thread),
    // 16 lanes sweep 64 floats (256B contiguous) per row, h doubles to 128.
    const int row = t >> 4;                      // 0..31
    const int k4  = (t & 15) * 4;

    float4 xr[2][2], ur[2][2], wr[2][2];         // [set][h]
    auto load_regs = [&](int c, int set) {
        #pragma unroll
        for (int h = 0; h < 2; ++h) {
            const int gk = c * CH + h * 64 + k4;
            xr[set][h] = *(const float4*)&x[(size_t)(mBase + row) * IN_SZ + gk];
            ur[set][h] = *(const float4*)&u[(size_t)(nBase + row) * IN_SZ + gk];
            wr[set][h] = *(const float4*)&w[(size_t)(nBase + row) * IN_SZ + gk];
        }
    };

    auto write_lds = [&](int buf, int set) {
        #pragma unroll
        for (int h = 0; h < 2; ++h) {
            const int kl   = h * 64 + k4;
            const int sW   = kl >> 5;
            const int quad = (kl >> 3) & 3;
            const int j0   = kl & 7;
            const int frag = row >> 4;
            const int slot = quad * 16 + (((row & 15) ^ quad) & 15);
            float xv[4]  = {xr[set][h].x, xr[set][h].y, xr[set][h].z, xr[set][h].w};
            float uv[4]  = {ur[set][h].x, ur[set][h].y, ur[set][h].z, ur[set][h].w};
            float wv4[4] = {wr[set][h].x, wr[set][h].y, wr[set][h].z, wr[set][h].w};
            bf16x4 a0, a1, b0, b1;
            #pragma unroll
            for (int e = 0; e < 4; ++e) {
                float xe = xv[e], ue = uv[e], we = wv4[e];
                float u2 = ue * ue, p = ue * we;
                a0[e] = (__bf16)(xe * xe);
                a1[e] = (__bf16)xe;
                b0[e] = (__bf16)u2;
                b1[e] = (__bf16)(-2.f * u2 * we);
                rp = fmaf(p, p, rp);             // exact rank-1 term
            }
            *(bf16x4*)&Asm[buf][A_IDX(0, sW, frag, slot) + j0] = a0;
            *(bf16x4*)&Asm[buf][A_IDX(1, sW, frag, slot) + j0] = a1;
            *(bf16x4*)&Bsm[buf][B_IDX(0, sW, frag, slot) + j0] = b0;
            *(bf16x4*)&Bsm[buf][B_IDX(1, sW, frag, slot) + j0] = b1;
        }
    };

    // read slot (same swizzle) -> conflict-free b128 reads (R0-proven)
    const int r_quad = lane >> 4;
    const int r_slot = r_quad * 16 + (((lane & 15) ^ r_quad) & 15);

    auto compute = [&](int buf) {
        #pragma unroll
        for (int seg = 0; seg < 2; ++seg)
            #pragma unroll
            for (int sh = 0; sh < 2; ++sh) {
                bf16x8 am = *(const bf16x8*)&Asm[buf][A_IDX(seg, ks * 2 + sh, wm, r_slot)];
                bf16x8 bn = *(const bf16x8*)&Bsm[buf][B_IDX(seg, ks * 2 + sh, wn, r_slot)];
                acc = __builtin_amdgcn_mfma_f32_16x16x32_bf16(am, bn, acc, 0, 0, 0);
            }
    };

    // prologue: fill buf0, start set1; one barrier publishes buf0.
    load_regs(0, 0);
    write_lds(0, 0);
    load_regs(1, 1);
    __syncthreads();

    for (int c = 0; c < NKC; ++c) {
        if (c + 2 < NKC) load_regs(c + 2, c & 1);        // 2-deep prefetch
        compute(c & 1);                                  // read buf c
        if (c + 1 < NKC) write_lds((c + 1) & 1, (c + 1) & 1); // fill buf c+1
        __syncthreads();                                 // publish buf c+1;
                                                         // also closes reads of buf c
    }

    // rank-1 reduce: 16 lanes per o-row
    rp += __shfl_xor(rp, 1);
    rp += __shfl_xor(rp, 2);
    rp += __shfl_xor(rp, 4);
    rp += __shfl_xor(rp, 8);
    if ((lane & 15) == 0) r_lds[row] = rp;

    if (ks == 1)
        *(f32x4*)&accsm[((wm * 2 + wn) * 64 + lane) * 4] = acc;
    __syncthreads();

    if (ks == 0) {
        f32x4 o4 = *(const f32x4*)&accsm[((wm * 2 + wn) * 64 + lane) * 4];
        // C/D: col = lane&15 (o), row = quad*4 + reg (b) — verified mapping
        const int col = lane & 15, rq = lane >> 4;
        const int b = mBase + wm * 16 + rq * 4;
        const int o = nBase + wn * 16 + col;
        const float rv = r_lds[wn * 16 + col];
        const float a  = andor[o];
        const float cf = 1.f - 2.f * a;
        #pragma unroll
        for (int r = 0; r < 4; ++r) {
            float y = __expf(-(acc[r] + o4[r] + rv));
            out[(size_t)(b + r) * OUT_SZ + o] = fmaf(y, cf, a);
        }
    }
}

extern "C" void kernel_launch(void* const* d_in, const int* in_sizes, int n_in,
                              void* d_out, int out_size, void* d_ws, size_t ws_size,
                              hipStream_t stream) {
    const float* x = (const float*)d_in[0];   // [B, IN]
    const float* w = (const float*)d_in[1];   // [OUT, IN]
    const float* u = (const float*)d_in[2];   // [OUT, IN]
    const float* a = (const float*)d_in[3];   // [1, OUT]
    float* out = (float*)d_out;               // [B, OUT]

    rbf_one<<<dim3((B_SZ / MB) * (OUT_SZ / NB)), dim3(512), 0, stream>>>(
        x, w, u, a, out);
}